// Round 4
// baseline (53.282 us; speedup 1.0000x reference)
//
#include <hip/hip_runtime.h>
#include <hip/hip_bf16.h>

// RotateChordVarLen: x [T, 256] f32, 16 tracks of 16 floats.
// out[t, track i] = x[start + (pos + shift_i) % len, track i],
// shift_0 = 0, shift_i = 2^(i-1).
//
// Persistent-chunk mapping: each wave owns CHUNK=16 consecutive tokens.
// lane l -> track l/4, float4 quad l%4. The expensive part (segment scan +
// 32-bit div for the initial (pos+shift)%len) runs ONCE per wave; inside the
// chunk the source position just increments with a circular wrap test
// (consecutive tokens -> consecutive source rows). Writes are coalesced
// 1 KiB/wave streaming stores; reads are 16 x 64B chunks advancing 1 KiB per
// token. Grid = 2048 blocks = 8192 waves = full 32-wave/CU residency
// (launch_bounds caps VGPR<=64), so 128B-line partner tokens (up to 8192
// apart) stay temporally close for L2/L3 pairing.

typedef float f32x4 __attribute__((ext_vector_type(4)));

#define CHUNK 16

__global__ __launch_bounds__(256, 8) void
rotate_chord_kernel(const float* __restrict__ x,
                    const int* __restrict__ lengths,
                    float* __restrict__ out,
                    int T, int B) {
    int wave  = (blockIdx.x * blockDim.x + threadIdx.x) >> 6;
    int lane  = threadIdx.x & 63;
    int track = lane >> 2;               // 0..15
    int quad  = lane & 3;                // 0..3

    int t_begin = wave * CHUNK;
    if (t_begin >= T) return;
    int t_end = t_begin + CHUNK;
    if (t_end > T) t_end = T;

    unsigned shift = (track == 0) ? 0u : (1u << (track - 1));
    int col = track * 16 + quad * 4;

    // Segment containing t_begin (B=8: tiny scan, once per wave).
    int start = 0, len = 1, acc = 0;
    for (int b = 0; b < B; ++b) {
        int L = lengths[b];
        if (t_begin >= acc) { start = acc; len = L; }
        acc += L;
    }
    // Initial source position within segment: (pos + shift) % len.
    unsigned sp = (unsigned)(t_begin - start) + shift;
    sp -= (sp / (unsigned)len) * (unsigned)len;

    const float* __restrict__ xs = x + col;
    float* __restrict__ os = out + lane * 4;

    if (t_end <= start + len && t_end == t_begin + CHUNK) {
        // Fast path: whole chunk inside one segment, full CHUNK trip count.
        size_t obase = (size_t)t_begin * 256;
#pragma unroll 4
        for (int i = 0; i < CHUNK; ++i) {
            f32x4 v = *reinterpret_cast<const f32x4*>(
                xs + (size_t)(start + (int)sp) * 256);
            *reinterpret_cast<f32x4*>(os + obase + (size_t)i * 256) = v;
            sp = (sp + 1 == (unsigned)len) ? 0u : sp + 1;
        }
    } else {
        // Slow path: chunk crosses a segment boundary (or ragged tail).
        for (int t = t_begin; t < t_end; ++t) {
            if (t >= start + len) {
                int s2 = 0, l2 = 1, a2 = 0;
                for (int b = 0; b < B; ++b) {
                    int L = lengths[b];
                    if (t >= a2) { s2 = a2; l2 = L; }
                    a2 += L;
                }
                start = s2; len = l2;
                sp = (unsigned)(t - start) + shift;
                sp -= (sp / (unsigned)len) * (unsigned)len;
            }
            f32x4 v = *reinterpret_cast<const f32x4*>(
                xs + (size_t)(start + (int)sp) * 256);
            *reinterpret_cast<f32x4*>(os + (size_t)t * 256) = v;
            sp = (sp + 1 == (unsigned)len) ? 0u : sp + 1;
        }
    }
}

extern "C" void kernel_launch(void* const* d_in, const int* in_sizes, int n_in,
                              void* d_out, int out_size, void* d_ws, size_t ws_size,
                              hipStream_t stream) {
    const float* x       = (const float*)d_in[0];
    const int*   lengths = (const int*)d_in[1];
    float*       out     = (float*)d_out;

    const int D = 256;
    int T = in_sizes[0] / D;
    int B = in_sizes[1];

    // 4 waves/block, CHUNK tokens per wave -> 64 tokens per block.
    int blocks = (T + 4 * CHUNK - 1) / (4 * CHUNK);

    rotate_chord_kernel<<<blocks, 256, 0, stream>>>(x, lengths, out, T, B);
}

// Round 5
// 44.422 us; speedup vs baseline: 1.1994x; 1.1994x over previous
//
#include <hip/hip_runtime.h>
#include <hip/hip_bf16.h>

// RotateChordVarLen, inverse mapping: iterate over SOURCE rows.
// out[t, track i] = x[start + (pos_t + shift_i) % len, track i]
//   <=>  for source row s:  out[start + (pos_s - shift_i) % len, track i] = x[s, track i]
// shift_0 = 0, shift_i = 2^(i-1).
//
// One wave per source row: lane l reads x[s, 4l..4l+4) -- DENSE 1 KiB/wave
// streaming loads (sequential DRAM, prefetch-friendly, low latency).
// Lane l stores its float4 to destination token t_i of its track (i = l/4):
// scattered 64B-granular stores -- fire-and-forget, no wave stalls.
// Partner 64B halves of each 128B output line merge in L2/L3 (134 MB < L3),
// so HBM write volume stays 134 MB. This flips R1's scatter from the
// latency-critical read side to the latency-tolerant write side.

typedef float f32x4 __attribute__((ext_vector_type(4)));

__global__ __launch_bounds__(256) void
rotate_chord_inv_kernel(const float* __restrict__ x,
                        const int* __restrict__ lengths,
                        float* __restrict__ out,
                        int T, int B) {
    int gid = blockIdx.x * blockDim.x + threadIdx.x;
    int s   = gid >> 6;            // source row (wave-uniform)
    if (s >= T) return;
    int lane  = threadIdx.x & 63;
    int track = lane >> 2;         // 0..15
    // lane reads x[s, lane*4 .. lane*4+4)

    // Per-lane segment search over B (=8) segments.
    int start = 0, len = 1, acc = 0;
    for (int b = 0; b < B; ++b) {
        int L = lengths[b];
        if (s >= acc) { start = acc; len = L; }
        acc += L;
    }
    int s_pos = s - start;

    int shift = (track == 0) ? 0 : (1 << (track - 1));
    // dest pos = (s_pos - shift) mod len  (shift may exceed len)
    int d = (s_pos - shift) % len;
    if (d < 0) d += len;
    int t = start + d;

    // Dense read: 64 lanes x 16B = contiguous 1 KiB row.
    f32x4 v = *reinterpret_cast<const f32x4*>(x + (size_t)s * 256 + lane * 4);

    // Scattered write: this lane's 16B goes to (token t, same column).
    *reinterpret_cast<f32x4*>(out + (size_t)t * 256 + lane * 4) = v;
}

extern "C" void kernel_launch(void* const* d_in, const int* in_sizes, int n_in,
                              void* d_out, int out_size, void* d_ws, size_t ws_size,
                              hipStream_t stream) {
    const float* x       = (const float*)d_in[0];
    const int*   lengths = (const int*)d_in[1];
    float*       out     = (float*)d_out;

    const int D = 256;
    int T = in_sizes[0] / D;
    int B = in_sizes[1];

    long long total_threads = (long long)T * 64;
    int blocks = (int)((total_threads + 255) / 256);

    rotate_chord_inv_kernel<<<blocks, 256, 0, stream>>>(x, lengths, out, T, B);
}